// Round 1
// baseline (87.185 us; speedup 1.0000x reference)
//
#include <hip/hip_runtime.h>
#include <math.h>

#define N_G       5000
#define HH        512
#define WW        512
#define TILE      16
#define TDIM      32              // tiles per axis
#define NTILES    (TDIM * TDIM)  // 1024
#define GSTRIDE   12             // floats per gaussian record (48 B)
#define PAIR_CAP  (N_G * 8)      // r < 8 => <= 4 tiles/gaussian; 2x margin
#define ALPHA_TH  (1.0f / 255.0f)
#define TWO_PI_F  6.28318530717958647692f

// ---------------- kernel 0: zero tile counts (ws is poisoned 0xAA) ----------
__global__ __launch_bounds__(256) void k_zero(int* counts) {
    int i = blockIdx.x * blockDim.x + threadIdx.x;
    if (i < NTILES) counts[i] = 0;
}

// ---------------- kernel 1: per-gaussian params + tile count ----------------
__global__ __launch_bounds__(256) void k_prep(
    const float* __restrict__ xyz, const float* __restrict__ scal,
    const float* __restrict__ rot, const float* __restrict__ fdc,
    const float* __restrict__ opac, float* __restrict__ params,
    int* __restrict__ counts)
{
    int i = blockIdx.x * blockDim.x + threadIdx.x;
    if (i >= N_G) return;

    float mx = tanhf(xyz[2 * i + 0]);
    float my = tanhf(xyz[2 * i + 1]);
    float sx = fabsf(scal[2 * i + 0] + 0.5f);
    float sy = fabsf(scal[2 * i + 1] + 0.5f);
    float th = (1.0f / (1.0f + expf(-rot[i]))) * TWO_PI_F;

    float cx = 0.5f * ((mx + 1.0f) * (float)WW - 1.0f);
    float cy = 0.5f * ((my + 1.0f) * (float)HH - 1.0f);
    float cth = cosf(th), sth = sinf(th);
    float sx2 = sx * sx, sy2 = sy * sy;
    float a = cth * cth * sx2 + sth * sth * sy2;
    float b = cth * sth * (sx2 - sy2);
    float c = sth * sth * sx2 + cth * cth * sy2;
    float det = a * c - b * b;
    bool valid = det > 0.0f;
    float inv_det = valid ? 1.0f / fmaxf(det, 1e-12f) : 0.0f;
    float A = c * inv_det, B = -b * inv_det, C = a * inv_det;
    float op = opac[i];

    float* p = params + (size_t)i * GSTRIDE;
    p[0] = cx; p[1] = cy; p[2] = A; p[3] = B; p[4] = C; p[5] = op;
    p[6] = fdc[3 * i + 0]; p[7] = fdc[3 * i + 1]; p[8] = fdc[3 * i + 2];

    // conservative bounding radius: sigma >= |d|^2 / (2*lmax(Sigma));
    // pixel can pass alpha>1/255 only if |d| < sqrt(2*ln(255*op)*lmax)
    float radius = 0.0f;
    if (valid && op > ALPHA_TH) {
        float tau  = logf(op * 255.0f);
        float mid  = 0.5f * (a + c);
        float rad  = sqrtf(fmaxf(0.0f, 0.25f * (a - c) * (a - c) + b * b));
        float lmax = mid + rad;
        radius = sqrtf(fmaxf(0.0f, 2.0f * tau * lmax)) * 1.0001f + 0.01f;
    }
    p[9] = radius; p[10] = 0.0f; p[11] = 0.0f;

    if (radius > 0.0f) {
        int x0 = max(0,        (int)floorf((cx - radius) * (1.0f / TILE)));
        int x1 = min(TDIM - 1, (int)floorf((cx + radius) * (1.0f / TILE)));
        int y0 = max(0,        (int)floorf((cy - radius) * (1.0f / TILE)));
        int y1 = min(TDIM - 1, (int)floorf((cy + radius) * (1.0f / TILE)));
        for (int ty = y0; ty <= y1; ++ty)
            for (int tx = x0; tx <= x1; ++tx)
                atomicAdd(&counts[ty * TDIM + tx], 1);
    }
}

// ---------------- kernel 2: 1024-wide prefix scan -> offsets, cursors -------
__global__ __launch_bounds__(1024) void k_scan(
    const int* __restrict__ counts, int* __restrict__ offsets,
    int* __restrict__ cursor)
{
    __shared__ int s[NTILES];
    int tid = threadIdx.x;
    int v0 = counts[tid];
    s[tid] = v0;
    __syncthreads();
    for (int off = 1; off < NTILES; off <<= 1) {
        int v = (tid >= off) ? s[tid - off] : 0;
        __syncthreads();
        s[tid] += v;
        __syncthreads();
    }
    // inclusive scan in s[]
    offsets[tid + 1] = s[tid];
    if (tid == 0) offsets[0] = 0;
    cursor[tid] = s[tid] - v0;   // exclusive prefix = list start
}

// ---------------- kernel 3: scatter gaussian ids into tile lists ------------
__global__ __launch_bounds__(256) void k_scatter(
    const float* __restrict__ params, int* __restrict__ cursor,
    int* __restrict__ pairs)
{
    int i = blockIdx.x * blockDim.x + threadIdx.x;
    if (i >= N_G) return;
    const float* p = params + (size_t)i * GSTRIDE;
    float cx = p[0], cy = p[1], radius = p[9];
    if (radius <= 0.0f) return;
    int x0 = max(0,        (int)floorf((cx - radius) * (1.0f / TILE)));
    int x1 = min(TDIM - 1, (int)floorf((cx + radius) * (1.0f / TILE)));
    int y0 = max(0,        (int)floorf((cy - radius) * (1.0f / TILE)));
    int y1 = min(TDIM - 1, (int)floorf((cy + radius) * (1.0f / TILE)));
    for (int ty = y0; ty <= y1; ++ty)
        for (int tx = x0; tx <= x1; ++tx) {
            int pos = atomicAdd(&cursor[ty * TDIM + tx], 1);
            if (pos < PAIR_CAP) pairs[pos] = i;
        }
}

// ---------------- kernel 4: render one 16x16 tile per block -----------------
__global__ __launch_bounds__(256) void k_render(
    const float* __restrict__ params, const int* __restrict__ offsets,
    const int* __restrict__ pairs, float* __restrict__ out)
{
    int tx = blockIdx.x, ty = blockIdx.y;
    int t = ty * TDIM + tx;
    int lx = threadIdx.x & (TILE - 1);
    int ly = threadIdx.x >> 4;
    int w = tx * TILE + lx;
    int h = ty * TILE + ly;
    float fx = (float)w, fy = (float)h;

    int s = offsets[t];
    int e = offsets[t + 1];
    if (s > PAIR_CAP) s = PAIR_CAP;   // defensive (can't trigger by the math)
    if (e > PAIR_CAP) e = PAIR_CAP;

    float r0 = 0.0f, r1 = 0.0f, r2 = 0.0f;
    for (int k = s; k < e; ++k) {
        int gi = pairs[k];                       // block-uniform load
        const float* p = params + (size_t)gi * GSTRIDE;
        float dx = p[0] - fx;
        float dy = p[1] - fy;
        float sigma = 0.5f * (p[2] * dx * dx + p[4] * dy * dy) + p[3] * dx * dy;
        float alpha = p[5] * __expf(-sigma);
        bool pass = (sigma >= 0.0f) && (alpha > ALPHA_TH);
        float wgt = pass ? alpha : 0.0f;
        r0 += wgt * p[6];
        r1 += wgt * p[7];
        r2 += wgt * p[8];
    }

    int pix = h * WW + w;
    out[0 * HH * WW + pix] = fminf(fmaxf(r0, 0.0f), 1.0f);
    out[1 * HH * WW + pix] = fminf(fmaxf(r1, 0.0f), 1.0f);
    out[2 * HH * WW + pix] = fminf(fmaxf(r2, 0.0f), 1.0f);
}

extern "C" void kernel_launch(void* const* d_in, const int* in_sizes, int n_in,
                              void* d_out, int out_size, void* d_ws, size_t ws_size,
                              hipStream_t stream) {
    const float* xyz  = (const float*)d_in[0];   // (N,2)
    const float* scal = (const float*)d_in[1];   // (N,2)
    const float* rot  = (const float*)d_in[2];   // (N,1)
    const float* fdc  = (const float*)d_in[3];   // (N,3)
    const float* opac = (const float*)d_in[4];   // (N,1)
    float* out = (float*)d_out;                  // (1,3,512,512) fp32

    // workspace carve (~412 KB total)
    float* params  = (float*)d_ws;                       // N_G*12 floats
    int*   counts  = (int*)(params + N_G * GSTRIDE);     // 1024
    int*   offsets = counts + NTILES;                    // 1025
    int*   cursor  = offsets + NTILES + 1;               // 1024
    int*   pairs   = cursor + NTILES;                    // PAIR_CAP

    k_zero<<<dim3((NTILES + 255) / 256), dim3(256), 0, stream>>>(counts);
    k_prep<<<dim3((N_G + 255) / 256), dim3(256), 0, stream>>>(
        xyz, scal, rot, fdc, opac, params, counts);
    k_scan<<<dim3(1), dim3(1024), 0, stream>>>(counts, offsets, cursor);
    k_scatter<<<dim3((N_G + 255) / 256), dim3(256), 0, stream>>>(
        params, cursor, pairs);
    k_render<<<dim3(TDIM, TDIM), dim3(256), 0, stream>>>(
        params, offsets, pairs, out);
}

// Round 2
// 80.362 us; speedup vs baseline: 1.0849x; 1.0849x over previous
//
#include <hip/hip_runtime.h>
#include <math.h>

#define N_G       5000
#define HH        512
#define WW        512
#define TILE      16
#define TDIM      32              // tiles per axis (512/16)
#define NTILES    (TDIM * TDIM)   // 1024
#define ALPHA_TH  (1.0f / 255.0f)
#define TWO_PI_F  6.28318530717958647692f

// ---------------- kernel 1: per-gaussian derived params ---------------------
// rec[3*i+0] = (cx, cy, A, B)
// rec[3*i+1] = (C, op, col0, col1)
// rec[3*i+2] = (col2, 0, 0, 0)
// cull[i]    = (cx, cy, radius, 0)      radius==0 -> never renders
__global__ __launch_bounds__(256) void k_prep(
    const float* __restrict__ xyz, const float* __restrict__ scal,
    const float* __restrict__ rot, const float* __restrict__ fdc,
    const float* __restrict__ opac,
    float4* __restrict__ rec, float4* __restrict__ cull)
{
    int i = blockIdx.x * blockDim.x + threadIdx.x;
    if (i >= N_G) return;

    float mx = tanhf(xyz[2 * i + 0]);
    float my = tanhf(xyz[2 * i + 1]);
    float sx = fabsf(scal[2 * i + 0] + 0.5f);
    float sy = fabsf(scal[2 * i + 1] + 0.5f);
    float th = (1.0f / (1.0f + expf(-rot[i]))) * TWO_PI_F;

    float cx = 0.5f * ((mx + 1.0f) * (float)WW - 1.0f);
    float cy = 0.5f * ((my + 1.0f) * (float)HH - 1.0f);
    float cth = cosf(th), sth = sinf(th);
    float sx2 = sx * sx, sy2 = sy * sy;
    float a = cth * cth * sx2 + sth * sth * sy2;
    float b = cth * sth * (sx2 - sy2);
    float c = sth * sth * sx2 + cth * cth * sy2;
    float det = a * c - b * b;
    bool valid = det > 0.0f;
    float inv_det = valid ? 1.0f / fmaxf(det, 1e-12f) : 0.0f;
    float A = c * inv_det, B = -b * inv_det, C = a * inv_det;
    float op = opac[i];

    // conservative radius: sigma >= |d|^2 / (2*lmax(Sigma)); lmax = max eig.
    // pixel can pass alpha>1/255 only if |d| < sqrt(2*ln(255*op)*lmax)
    float radius = 0.0f;
    if (valid && op > ALPHA_TH) {
        float tau  = logf(op * 255.0f);
        float mid  = 0.5f * (a + c);
        float rad  = sqrtf(fmaxf(0.0f, 0.25f * (a - c) * (a - c) + b * b));
        float lmax = mid + rad;
        radius = sqrtf(fmaxf(0.0f, 2.0f * tau * lmax)) * 1.0001f + 0.01f;
    }

    rec[3 * i + 0] = make_float4(cx, cy, A, B);
    rec[3 * i + 1] = make_float4(C, op, fdc[3 * i + 0], fdc[3 * i + 1]);
    rec[3 * i + 2] = make_float4(fdc[3 * i + 2], 0.0f, 0.0f, 0.0f);
    cull[i]        = make_float4(cx, cy, radius, 0.0f);
}

// ---------------- kernel 2: fused cull + render, one block per 16x16 tile ---
__global__ __launch_bounds__(256) void k_render(
    const float4* __restrict__ rec, const float4* __restrict__ cull,
    float* __restrict__ out)
{
    __shared__ int list[N_G];
    __shared__ int cnt;

    int t  = blockIdx.x;
    int tx = t & (TDIM - 1);
    int ty = t >> 5;
    int lx = threadIdx.x & (TILE - 1);
    int ly = threadIdx.x >> 4;
    int w  = tx * TILE + lx;
    int h  = ty * TILE + ly;
    float fx = (float)w, fy = (float)h;

    // tile pixel-coordinate AABB (pixels are points at integer coords)
    float x0 = (float)(tx * TILE), x1 = (float)(tx * TILE + TILE - 1);
    float y0 = (float)(ty * TILE), y1 = (float)(ty * TILE + TILE - 1);

    if (threadIdx.x == 0) cnt = 0;
    __syncthreads();

    // cull all gaussians against this tile (coalesced float4 loads)
    for (int base = 0; base < N_G; base += 256) {
        int i = base + threadIdx.x;
        if (i < N_G) {
            float4 q = cull[i];
            float nx  = fminf(fmaxf(q.x, x0), x1);
            float ny  = fminf(fmaxf(q.y, y0), y1);
            float ddx = q.x - nx;
            float ddy = q.y - ny;
            if (ddx * ddx + ddy * ddy < q.z * q.z) {
                int p = atomicAdd(&cnt, 1);
                list[p] = i;
            }
        }
    }
    __syncthreads();
    int e = cnt;

    float r0 = 0.0f, r1 = 0.0f, r2 = 0.0f;
    for (int k = 0; k < e; ++k) {
        int gi = list[k];                      // LDS broadcast, block-uniform
        float4 pa = rec[3 * gi + 0];           // cx, cy, A, B
        float4 pb = rec[3 * gi + 1];           // C, op, c0, c1
        float4 pc = rec[3 * gi + 2];           // c2
        float dx = pa.x - fx;
        float dy = pa.y - fy;
        float sigma = 0.5f * (pa.z * dx * dx + pb.x * dy * dy) + pa.w * dx * dy;
        float alpha = pb.y * __expf(-sigma);
        bool pass = (sigma >= 0.0f) && (alpha > ALPHA_TH);
        float wg = pass ? alpha : 0.0f;
        r0 += wg * pb.z;
        r1 += wg * pb.w;
        r2 += wg * pc.x;
    }

    int pix = h * WW + w;
    out[0 * HH * WW + pix] = fminf(fmaxf(r0, 0.0f), 1.0f);
    out[1 * HH * WW + pix] = fminf(fmaxf(r1, 0.0f), 1.0f);
    out[2 * HH * WW + pix] = fminf(fmaxf(r2, 0.0f), 1.0f);
}

extern "C" void kernel_launch(void* const* d_in, const int* in_sizes, int n_in,
                              void* d_out, int out_size, void* d_ws, size_t ws_size,
                              hipStream_t stream) {
    const float* xyz  = (const float*)d_in[0];   // (N,2)
    const float* scal = (const float*)d_in[1];   // (N,2)
    const float* rot  = (const float*)d_in[2];   // (N,1)
    const float* fdc  = (const float*)d_in[3];   // (N,3)
    const float* opac = (const float*)d_in[4];   // (N,1)
    float* out = (float*)d_out;                  // (1,3,512,512) fp32

    // workspace carve: rec = 3*N_G float4 (240 KB), cull = N_G float4 (80 KB)
    float4* rec  = (float4*)d_ws;
    float4* cull = rec + 3 * N_G;

    k_prep<<<dim3((N_G + 255) / 256), dim3(256), 0, stream>>>(
        xyz, scal, rot, fdc, opac, rec, cull);
    k_render<<<dim3(NTILES), dim3(256), 0, stream>>>(rec, cull, out);
}